// Round 19
// baseline (114.105 us; speedup 1.0000x reference)
//
#include <hip/hip_runtime.h>

#define P 7
#define NCH 256
#define NPP 49
#define LDS_CAP 1280   // max Hr*(Wr|1) <= ~910 (level-geometry bound, r9-proven)

__global__ __launch_bounds__(256) void pooler_kernel(
    const float* __restrict__ boxes,
    const int* __restrict__ batch_ids,
    const float* __restrict__ g0, const float* __restrict__ g1,
    const float* __restrict__ g2, const float* __restrict__ g3,
    float* __restrict__ out)
{
    __shared__ float sreg[4][LDS_CAP];   // 20 KB; sreg[wy] is WAVE-PRIVATE

    const int n    = blockIdx.y;          // box
    const int cg   = blockIdx.x;          // channel group 0..63
    const int lane = threadIdx.x;         // 0..63
    const int wy   = threadIdx.y;         // wave index = channel within group
    const int c    = (cg << 2) | wy;

    // ---- box + level (uniform within block) ----
    const float x1i = boxes[n*4+0], y1i = boxes[n*4+1];
    const float x2i = boxes[n*4+2], y2i = boxes[n*4+3];
    const float area = (x2i - x1i) * (y2i - y1i);
    float lvlf = floorf(4.0f + log2f(sqrtf(area) / 224.0f + 1e-6f));
    lvlf = fminf(fmaxf(lvlf, 2.0f), 5.0f);
    const int lvl = (int)lvlf - 2;        // 0..3

    const float* feat = (lvl==0) ? g0 : (lvl==1) ? g1 : (lvl==2) ? g2 : g3;
    const int    L    = (lvl==0) ? 200 : (lvl==1) ? 100 : (lvl==2) ? 50 : 25;
    const float scale = (lvl==0) ? 0.25f : (lvl==1) ? 0.125f
                      : (lvl==2) ? 0.0625f : 0.03125f;
    const int b = batch_ids[n];

    const float x1 = x1i * scale, y1 = y1i * scale;
    const float bw = fmaxf(x2i*scale - x1, 1.0f) * (1.0f/7.0f);
    const float bh = fmaxf(y2i*scale - y1, 1.0f) * (1.0f/7.0f);
    const float Lf = (float)L, Lm1 = Lf - 1.0f;
    const int   Lm2 = L - 2;

    // ---- region bounds (monotone prep over samples g in [0.25, 6.75]) ----
    const int rx0 = min((int)fminf(fmaxf(x1 + 0.25f*bw, 0.0f), Lm1), Lm2);
    const int rx1 = min((int)fminf(fmaxf(x1 + 6.75f*bw, 0.0f), Lm1), Lm2);
    const int ry0 = min((int)fminf(fmaxf(y1 + 0.25f*bh, 0.0f), Lm1), Lm2);
    const int ry1 = min((int)fminf(fmaxf(y1 + 6.75f*bh, 0.0f), Lm1), Lm2);
    const int Wr = rx1 - rx0 + 2;
    const int Hr = ry1 - ry0 + 2;
    const int stride = Wr | 1;            // odd row stride -> bank-spread
    const int Hm1 = Hr - 1;

    const float* gp = feat + ((size_t)b * NCH + c) * (size_t)(L * L)
                    + (size_t)ry0 * L + rx0;
    float* sp = sreg[wy];

    // ---- stage region -> LDS: uniform row loop, clamped tail, NO guards ----
    // rc = min(r+j, Hr-1): tail loads/writes row Hr-1's correct data again.
    // Row bases are wave-uniform (SALU); lane = col -> coalesced, conflict-free.
    for (int r = 0; r < Hr; r += 8) {
        int rr[8];
#pragma unroll
        for (int j = 0; j < 8; ++j) rr[j] = min(r + j, Hm1);
        for (int c0 = lane; c0 < Wr; c0 += 64) {   // 1 iter when Wr<=64
            float v[8];
#pragma unroll
            for (int j = 0; j < 8; ++j) v[j] = gp[(size_t)rr[j] * L + c0];
#pragma unroll
            for (int j = 0; j < 8; ++j) sp[rr[j] * stride + c0] = v[j];
        }
    }
    // NO __syncthreads(): sreg[wy] written and read only by wave wy;
    // compiler-inserted vmcnt/lgkmcnt orders load -> ds_write -> ds_read.

    // ---- bilinear interpolation from LDS (lanes 0..48 = bins) ----
    if (lane < NPP) {
        const int py = lane / P;
        const int px = lane - py * P;

        int   y0[2], x0[2];
        float fy[2], hy[2], vy[2], fx[2], hx[2], vx[2];
#pragma unroll
        for (int s = 0; s < 2; ++s) {
            const float yc = y1 + ((float)py + (s ? 0.75f : 0.25f)) * bh;
            vy[s] = (yc > -1.0f && yc < Lf) ? 1.0f : 0.0f;
            const float ycc = fminf(fmaxf(yc, 0.0f), Lm1);
            y0[s] = min((int)ycc, Lm2);
            fy[s] = ycc - (float)y0[s];
            hy[s] = 1.0f - fy[s];

            const float xc = x1 + ((float)px + (s ? 0.75f : 0.25f)) * bw;
            vx[s] = (xc > -1.0f && xc < Lf) ? 1.0f : 0.0f;
            const float xcc = fminf(fmaxf(xc, 0.0f), Lm1);
            x0[s] = min((int)xcc, Lm2);
            fx[s] = xcc - (float)x0[s];
            hx[s] = 1.0f - fx[s];
        }

        float acc = 0.0f;
#pragma unroll
        for (int sy = 0; sy < 2; ++sy) {
            const int rowa = (y0[sy] - ry0) * stride - rx0;
#pragma unroll
            for (int sx = 0; sx < 2; ++sx) {
                const int a = rowa + x0[sx];
                const float v00 = sp[a];
                const float v01 = sp[a + 1];
                const float v10 = sp[a + stride];
                const float v11 = sp[a + stride + 1];
                acc += (vy[sy] * vx[sx])
                     * (hy[sy] * (hx[sx] * v00 + fx[sx] * v01)
                      + fy[sy] * (hx[sx] * v10 + fx[sx] * v11));
            }
        }
        out[((size_t)n * NCH + c) * NPP + lane] = acc * 0.25f;
    }
}

extern "C" void kernel_launch(void* const* d_in, const int* in_sizes, int n_in,
                              void* d_out, int out_size, void* d_ws, size_t ws_size,
                              hipStream_t stream) {
    const float* boxes     = (const float*)d_in[0];
    const int*   batch_ids = (const int*)d_in[1];
    const float* g0        = (const float*)d_in[2];
    const float* g1        = (const float*)d_in[3];
    const float* g2        = (const float*)d_in[4];
    const float* g3        = (const float*)d_in[5];
    float* out = (float*)d_out;

    const int N = in_sizes[0] / 4;                 // 512
    dim3 block(64, 4);                             // 4 waves = 4 channels
    dim3 grid(NCH / 4, N);                         // (64, 512)
    pooler_kernel<<<grid, block, 0, stream>>>(boxes, batch_ids, g0, g1, g2, g3, out);
}

// Round 20
// 62.044 us; speedup vs baseline: 1.8391x; 1.8391x over previous
//
#include <hip/hip_runtime.h>

#define P 7
#define NCH 256
#define NPP 49
#define LDS_CAP 1280   // max Hr*(Wr|1) <= ~950 (level-geometry bound, r9)

typedef float f2 __attribute__((ext_vector_type(2), aligned(4)));

__device__ __forceinline__ int rfl(int x) { return __builtin_amdgcn_readfirstlane(x); }

__global__ __launch_bounds__(256) void pooler_kernel(
    const float* __restrict__ boxes,
    const int* __restrict__ batch_ids,
    const float* __restrict__ g0, const float* __restrict__ g1,
    const float* __restrict__ g2, const float* __restrict__ g3,
    float* __restrict__ out)
{
    __shared__ float sreg[4][LDS_CAP];   // 20 KB; sreg[wy] is WAVE-PRIVATE

    const int n    = blockIdx.y;          // box
    const int cg   = blockIdx.x;          // channel group 0..63
    const int lane = threadIdx.x;         // 0..63
    const int wy   = threadIdx.y;         // wave index = channel within group
    const int c    = (cg << 2) | wy;

    // ---- box + level (wave-uniform values; force into SGPRs via rfl) ----
    const float x1i = boxes[n*4+0], y1i = boxes[n*4+1];
    const float x2i = boxes[n*4+2], y2i = boxes[n*4+3];
    const float area = (x2i - x1i) * (y2i - y1i);
    float lvlf = floorf(4.0f + log2f(sqrtf(area) / 224.0f + 1e-6f));
    lvlf = fminf(fmaxf(lvlf, 2.0f), 5.0f);
    const int lvl = rfl((int)lvlf - 2);   // SGPR -> uniform selects below

    const float* feat = (lvl==0) ? g0 : (lvl==1) ? g1 : (lvl==2) ? g2 : g3;
    const int    L    = (lvl==0) ? 200 : (lvl==1) ? 100 : (lvl==2) ? 50 : 25;
    const float scale = (lvl==0) ? 0.25f : (lvl==1) ? 0.125f
                      : (lvl==2) ? 0.0625f : 0.03125f;
    const int b = batch_ids[n];

    const float x1 = x1i * scale, y1 = y1i * scale;
    const float bw = fmaxf(x2i*scale - x1, 1.0f) * (1.0f/7.0f);
    const float bh = fmaxf(y2i*scale - y1, 1.0f) * (1.0f/7.0f);
    const float Lf = (float)L, Lm1 = Lf - 1.0f;
    const int   Lm2 = L - 2;

    // ---- region bounds -> SGPRs ----
    const int rx0 = rfl(min((int)fminf(fmaxf(x1 + 0.25f*bw, 0.0f), Lm1), Lm2));
    const int rx1 = rfl(min((int)fminf(fmaxf(x1 + 6.75f*bw, 0.0f), Lm1), Lm2));
    const int ry0 = rfl(min((int)fminf(fmaxf(y1 + 0.25f*bh, 0.0f), Lm1), Lm2));
    const int ry1 = rfl(min((int)fminf(fmaxf(y1 + 6.75f*bh, 0.0f), Lm1), Lm2));
    const int Wr  = rx1 - rx0 + 2;        // uniform (SALU)
    const int Hr  = ry1 - ry0 + 2;
    const int stride = Wr | 1;            // odd -> bank-spread on reads
    const int Hm1 = Hr - 1;
    const int Wc  = Wr - 2;               // clamp bound for f2 pairs

    // plane offset fits int32: max (511*256+255)*40000 + 40000 < 2^31? No:
    // (b*NCH + c) <= 511; *LL(<=40000) = 20.44M; + ry0*L + rx0 < 40040 -> OK.
    const int poff = rfl((b * NCH + c) * (L * L) + ry0 * L + rx0);
    const float* gp = feat + poff;        // SGPR base -> saddr load form
    float* sp = sreg[wy];

    // ---- stage region -> LDS: SGPR row-walk, f2 lanes, no guards ----
    if (Wr > 32) {
        // wide: lane pair covers 2 cols; 1-2 col passes; 4 rows in flight
        const int c0 = lane << 1;
        for (int cb = 0; cb < Wr; cb += 128) {
            const int ccc = min(cb + c0, Wc);          // clamped: always valid
            for (int r = 0; r < Hr; r += 4) {
                int rr[4]; f2 v[4];
#pragma unroll
                for (int j = 0; j < 4; ++j) rr[j] = min(r + j, Hm1);  // SALU
#pragma unroll
                for (int j = 0; j < 4; ++j)
                    v[j] = *(const f2*)(gp + rr[j] * L + ccc);        // saddr
#pragma unroll
                for (int j = 0; j < 4; ++j) {
                    const int a = rr[j] * stride + ccc;
                    sp[a] = v[j].x; sp[a + 1] = v[j].y;
                }
            }
        }
    } else {
        // narrow: 4 rows/iter (sub = lane>>4), 8-row double groups for depth
        const int sub  = lane >> 4;                    // 0..3
        const int cc   = min((lane & 15) << 1, Wc);    // cols 0..30 clamped
        const int gofs = sub * L + cc;                 // hoisted VGPR offset
        const int lofs = sub * stride + cc;
        int r = 0;
        for (; r + 8 <= Hr; r += 8) {
            const f2 vA = *(const f2*)(gp + r * L + gofs);
            const f2 vB = *(const f2*)(gp + (r + 4) * L + gofs);
            const int aA = r * stride + lofs;
            const int aB = (r + 4) * stride + lofs;
            sp[aA] = vA.x; sp[aA + 1] = vA.y;
            sp[aB] = vB.x; sp[aB + 1] = vB.y;
        }
        for (; r < Hr; r += 4) {
            if (sub < Hr - r) {                        // tail rows, predicated
                const f2 v = *(const f2*)(gp + r * L + gofs);
                const int a = r * stride + lofs;
                sp[a] = v.x; sp[a + 1] = v.y;
            }
        }
    }
    // NO __syncthreads(): sreg[wy] written and read only by wave wy
    // (proven r15/r16/r18); in-wave waitcnt orders load -> ds_write -> ds_read.

    // ---- bilinear interpolation from LDS (lanes 0..48 = bins) ----
    if (lane < NPP) {
        const int py = lane / P;
        const int px = lane - py * P;

        int   y0[2], x0[2];
        float fy[2], hy[2], vy[2], fx[2], hx[2], vx[2];
#pragma unroll
        for (int s = 0; s < 2; ++s) {
            const float yc = y1 + ((float)py + (s ? 0.75f : 0.25f)) * bh;
            vy[s] = (yc > -1.0f && yc < Lf) ? 1.0f : 0.0f;
            const float ycc = fminf(fmaxf(yc, 0.0f), Lm1);
            y0[s] = min((int)ycc, Lm2);
            fy[s] = ycc - (float)y0[s];
            hy[s] = 1.0f - fy[s];

            const float xc = x1 + ((float)px + (s ? 0.75f : 0.25f)) * bw;
            vx[s] = (xc > -1.0f && xc < Lf) ? 1.0f : 0.0f;
            const float xcc = fminf(fmaxf(xc, 0.0f), Lm1);
            x0[s] = min((int)xcc, Lm2);
            fx[s] = xcc - (float)x0[s];
            hx[s] = 1.0f - fx[s];
        }

        float acc = 0.0f;
#pragma unroll
        for (int sy = 0; sy < 2; ++sy) {
            const int rowa = (y0[sy] - ry0) * stride - rx0;
#pragma unroll
            for (int sx = 0; sx < 2; ++sx) {
                const int a = rowa + x0[sx];
                const float v00 = sp[a];
                const float v01 = sp[a + 1];
                const float v10 = sp[a + stride];
                const float v11 = sp[a + stride + 1];
                acc += (vy[sy] * vx[sx])
                     * (hy[sy] * (hx[sx] * v00 + fx[sx] * v01)
                      + fy[sy] * (hx[sx] * v10 + fx[sx] * v11));
            }
        }
        out[((size_t)n * NCH + c) * NPP + lane] = acc * 0.25f;
    }
}

extern "C" void kernel_launch(void* const* d_in, const int* in_sizes, int n_in,
                              void* d_out, int out_size, void* d_ws, size_t ws_size,
                              hipStream_t stream) {
    const float* boxes     = (const float*)d_in[0];
    const int*   batch_ids = (const int*)d_in[1];
    const float* g0        = (const float*)d_in[2];
    const float* g1        = (const float*)d_in[3];
    const float* g2        = (const float*)d_in[4];
    const float* g3        = (const float*)d_in[5];
    float* out = (float*)d_out;

    const int N = in_sizes[0] / 4;                 // 512
    dim3 block(64, 4);                             // 4 waves = 4 channels
    dim3 grid(NCH / 4, N);                         // (64, 512)
    pooler_kernel<<<grid, block, 0, stream>>>(boxes, batch_ids, g0, g1, g2, g3, out);
}

// Round 22
// 57.492 us; speedup vs baseline: 1.9847x; 1.0792x over previous
//
#include <hip/hip_runtime.h>

#define P 7
#define NCH 256
#define NPP 49
#define CHIT 4         // channels per wave (serial)
#define LDS_CAP 1280   // max Hr*(Wr|1) <= ~950 (level-geometry bound, r9)

typedef float f2 __attribute__((ext_vector_type(2), aligned(4)));

__device__ __forceinline__ int rfl(int x) { return __builtin_amdgcn_readfirstlane(x); }

__global__ __launch_bounds__(256) void pooler_kernel(
    const float* __restrict__ boxes,
    const int* __restrict__ batch_ids,
    const float* __restrict__ g0, const float* __restrict__ g1,
    const float* __restrict__ g2, const float* __restrict__ g3,
    float* __restrict__ out)
{
    __shared__ float sreg[4][LDS_CAP];   // 20 KB; sreg[wy] is WAVE-PRIVATE

    const int n    = blockIdx.y;          // box
    const int cq   = blockIdx.x;          // channel quad-group 0..15
    const int lane = threadIdx.x;         // 0..63
    const int wy   = threadIdx.y;         // wave index
    // wave's channels: c = cq*16 + it*4 + wy, it = 0..3

    // ---- box + level (wave-uniform; force SGPR via rfl) ----
    const float x1i = boxes[n*4+0], y1i = boxes[n*4+1];
    const float x2i = boxes[n*4+2], y2i = boxes[n*4+3];
    const float area = (x2i - x1i) * (y2i - y1i);
    float lvlf = floorf(4.0f + log2f(sqrtf(area) / 224.0f + 1e-6f));
    lvlf = fminf(fmaxf(lvlf, 2.0f), 5.0f);
    const int lvl = rfl((int)lvlf - 2);   // 0..3

    const float* feat = (lvl==0) ? g0 : (lvl==1) ? g1 : (lvl==2) ? g2 : g3;
    const int    L    = (lvl==0) ? 200 : (lvl==1) ? 100 : (lvl==2) ? 50 : 25;
    const float scale = (lvl==0) ? 0.25f : (lvl==1) ? 0.125f
                      : (lvl==2) ? 0.0625f : 0.03125f;
    const int b  = batch_ids[n];
    const int LL = L * L;

    const float x1 = x1i * scale, y1 = y1i * scale;
    const float bw = fmaxf(x2i*scale - x1, 1.0f) * (1.0f/7.0f);
    const float bh = fmaxf(y2i*scale - y1, 1.0f) * (1.0f/7.0f);
    const float Lf = (float)L, Lm1 = Lf - 1.0f;
    const int   Lm2 = L - 2;

    // ---- region bounds -> SGPRs (once) ----
    const int rx0 = rfl(min((int)fminf(fmaxf(x1 + 0.25f*bw, 0.0f), Lm1), Lm2));
    const int rx1 = rfl(min((int)fminf(fmaxf(x1 + 6.75f*bw, 0.0f), Lm1), Lm2));
    const int ry0 = rfl(min((int)fminf(fmaxf(y1 + 0.25f*bh, 0.0f), Lm1), Lm2));
    const int ry1 = rfl(min((int)fminf(fmaxf(y1 + 6.75f*bh, 0.0f), Lm1), Lm2));
    const int Wr  = rx1 - rx0 + 2;
    const int Hr  = ry1 - ry0 + 2;
    const int stride = Wr | 1;            // odd -> bank-spread
    const int Hm1 = Hr - 1;
    const int Wc  = Wr - 2;               // f2 clamp bound

    // ---- interp prep ONCE (channel-independent): weights + LDS addrs ----
    const int py = (lane < NPP) ? lane / P : 6;
    const int px = (lane < NPP) ? lane - py * P : 6;
    float wta[2][2], wtb[2][2], wtc[2][2], wtd[2][2];
    int   adr[2][2];
    {
        int   y0[2], x0[2];
        float fy[2], hy[2], vy[2], fx[2], hx[2], vx[2];
#pragma unroll
        for (int s = 0; s < 2; ++s) {
            const float yc = y1 + ((float)py + (s ? 0.75f : 0.25f)) * bh;
            vy[s] = (yc > -1.0f && yc < Lf) ? 1.0f : 0.0f;
            const float ycc = fminf(fmaxf(yc, 0.0f), Lm1);
            y0[s] = min((int)ycc, Lm2);
            fy[s] = ycc - (float)y0[s];
            hy[s] = 1.0f - fy[s];

            const float xc = x1 + ((float)px + (s ? 0.75f : 0.25f)) * bw;
            vx[s] = (xc > -1.0f && xc < Lf) ? 1.0f : 0.0f;
            const float xcc = fminf(fmaxf(xc, 0.0f), Lm1);
            x0[s] = min((int)xcc, Lm2);
            fx[s] = xcc - (float)x0[s];
            hx[s] = 1.0f - fx[s];
        }
#pragma unroll
        for (int sy = 0; sy < 2; ++sy)
#pragma unroll
        for (int sx = 0; sx < 2; ++sx) {
            const float w = 0.25f * vy[sy] * vx[sx];
            wta[sy][sx] = w * hy[sy] * hx[sx];
            wtb[sy][sx] = w * hy[sy] * fx[sx];
            wtc[sy][sx] = w * fy[sy] * hx[sx];
            wtd[sy][sx] = w * fy[sy] * fx[sx];
            adr[sy][sx] = (y0[sy] - ry0) * stride - rx0 + x0[sx];
        }
    }

    // ---- staging lane geometry ONCE ----
    const int cw0 = lane << 1;                     // wide-branch col pair
    const int sub  = lane >> 4;                    // narrow-branch row-sub 0..3
    const int ccn  = min((lane & 15) << 1, Wc);    // narrow cols, clamped
    const int gofs = sub * L + ccn;
    const int lofs = sub * stride + ccn;

    float* sp = sreg[wy];
    const int c_first = cq * (CHIT * 4) + wy;
    size_t ob = ((size_t)n * NCH + c_first) * NPP + lane;

    for (int it = 0; it < CHIT; ++it) {
        const int c    = c_first + (it << 2);
        const int poff = rfl((b * NCH + c) * LL + ry0 * L + rx0);  // SALU
        const float* gp = feat + poff;

        // ---- stage region -> LDS (SGPR base, precomputed lane offsets) ----
        if (Wr > 32) {
            for (int cb = 0; cb < Wr; cb += 128) {
                const int ccc = min(cb + cw0, Wc);
                for (int r = 0; r < Hr; r += 4) {
                    int rr[4]; f2 v[4];
#pragma unroll
                    for (int j = 0; j < 4; ++j) rr[j] = min(r + j, Hm1);
#pragma unroll
                    for (int j = 0; j < 4; ++j)
                        v[j] = *(const f2*)(gp + rr[j] * L + ccc);
#pragma unroll
                    for (int j = 0; j < 4; ++j) {
                        const int a = rr[j] * stride + ccc;
                        sp[a] = v[j].x; sp[a + 1] = v[j].y;
                    }
                }
            }
        } else {
            int r = 0;
            for (; r + 8 <= Hr; r += 8) {
                const f2 vA = *(const f2*)(gp + r * L + gofs);
                const f2 vB = *(const f2*)(gp + (r + 4) * L + gofs);
                const int aA = r * stride + lofs;
                const int aB = (r + 4) * stride + lofs;
                sp[aA] = vA.x; sp[aA + 1] = vA.y;
                sp[aB] = vB.x; sp[aB + 1] = vB.y;
            }
            for (; r < Hr; r += 4) {
                if (sub < Hr - r) {
                    const f2 v = *(const f2*)(gp + r * L + gofs);
                    const int a = r * stride + lofs;
                    sp[a] = v.x; sp[a + 1] = v.y;
                }
            }
        }
        // NO barrier: sreg[wy] is wave-private; per-wave DS ops are in program
        // order, so iter k's ds_reads complete before iter k+1's overwrites.

        // ---- interp from LDS: 16 ds_read + fma chain, weights precomputed ----
        if (lane < NPP) {
            float acc = 0.0f;
#pragma unroll
            for (int sy = 0; sy < 2; ++sy)
#pragma unroll
            for (int sx = 0; sx < 2; ++sx) {
                const int a = adr[sy][sx];
                acc += wta[sy][sx] * sp[a]
                     + wtb[sy][sx] * sp[a + 1]
                     + wtc[sy][sx] * sp[a + stride]
                     + wtd[sy][sx] * sp[a + stride + 1];
            }
            out[ob] = acc;
        }
        ob += (size_t)4 * NPP;                     // next channel (+4) output
    }
}

extern "C" void kernel_launch(void* const* d_in, const int* in_sizes, int n_in,
                              void* d_out, int out_size, void* d_ws, size_t ws_size,
                              hipStream_t stream) {
    const float* boxes     = (const float*)d_in[0];
    const int*   batch_ids = (const int*)d_in[1];
    const float* g0        = (const float*)d_in[2];
    const float* g1        = (const float*)d_in[3];
    const float* g2        = (const float*)d_in[4];
    const float* g3        = (const float*)d_in[5];
    float* out = (float*)d_out;

    const int N = in_sizes[0] / 4;                 // 512
    dim3 block(64, 4);                             // 4 waves; wave = 4 channels serial
    dim3 grid(NCH / (CHIT * 4), N);                // (16, 512)
    pooler_kernel<<<grid, block, 0, stream>>>(boxes, batch_ids, g0, g1, g2, g3, out);
}

// Round 23
// 52.673 us; speedup vs baseline: 2.1663x; 1.0915x over previous
//
#include <hip/hip_runtime.h>

#define P 7
#define NCH 256
#define NPP 49
#define CHIT 4          // channels per wave (serial)
#define LDS_CAP 2048    // worst Hr*stride = 1936 (L=200 tall-narrow), proven r23

typedef float f2 __attribute__((ext_vector_type(2), aligned(8)));
typedef float f4 __attribute__((ext_vector_type(4), aligned(16)));

__device__ __forceinline__ int rfl(int x) { return __builtin_amdgcn_readfirstlane(x); }

__global__ __launch_bounds__(256) void pooler_kernel(
    const float* __restrict__ boxes,
    const int* __restrict__ batch_ids,
    const float* __restrict__ g0, const float* __restrict__ g1,
    const float* __restrict__ g2, const float* __restrict__ g3,
    float* __restrict__ out)
{
    __shared__ __align__(16) float sreg[4][LDS_CAP];   // 32 KB; wave-private rows

    const int n    = blockIdx.y;          // box
    const int cq   = blockIdx.x;          // channel quad-group 0..15
    const int lane = threadIdx.x;         // 0..63
    const int wy   = threadIdx.y;         // wave index

    // ---- box + level (wave-uniform; SGPR via rfl) ----
    const float x1i = boxes[n*4+0], y1i = boxes[n*4+1];
    const float x2i = boxes[n*4+2], y2i = boxes[n*4+3];
    const float area = (x2i - x1i) * (y2i - y1i);
    float lvlf = floorf(4.0f + log2f(sqrtf(area) / 224.0f + 1e-6f));
    lvlf = fminf(fmaxf(lvlf, 2.0f), 5.0f);
    const int lvl = rfl((int)lvlf - 2);   // 0..3

    const float* feat = (lvl==0) ? g0 : (lvl==1) ? g1 : (lvl==2) ? g2 : g3;
    const int    L    = (lvl==0) ? 200 : (lvl==1) ? 100 : (lvl==2) ? 50 : 25;
    const float scale = (lvl==0) ? 0.25f : (lvl==1) ? 0.125f
                      : (lvl==2) ? 0.0625f : 0.03125f;
    const int b  = batch_ids[n];
    const int LL = L * L;

    const float x1 = x1i * scale, y1 = y1i * scale;
    const float bw = fmaxf(x2i*scale - x1, 1.0f) * (1.0f/7.0f);
    const float bh = fmaxf(y2i*scale - y1, 1.0f) * (1.0f/7.0f);
    const float Lf = (float)L, Lm1 = Lf - 1.0f;
    const int   Lm2 = L - 2;

    // ---- region bounds -> SGPRs ----
    const int rx0 = rfl(min((int)fminf(fmaxf(x1 + 0.25f*bw, 0.0f), Lm1), Lm2));
    const int rx1 = rfl(min((int)fminf(fmaxf(x1 + 6.75f*bw, 0.0f), Lm1), Lm2));
    const int ry0 = rfl(min((int)fminf(fmaxf(y1 + 0.25f*bh, 0.0f), Lm1), Lm2));
    const int ry1 = rfl(min((int)fminf(fmaxf(y1 + 6.75f*bh, 0.0f), Lm1), Lm2));
    const int Hr  = ry1 - ry0 + 2;
    const int Hm1 = Hr - 1;

    // ---- level-dependent aligned region layout (all SALU) ----
    // lvl 0/1 (L=200/100): L%4==0, LL%4==0 -> 16B-provable -> f4 staging
    // lvl 2   (L=50):      L%2==0, LL%2==0 ->  8B-provable -> f2 staging
    // lvl 3   (L=25):      no parity guarantee            -> b32 staging
    int rx0a, WrA, stride;
    if (lvl <= 1) {
        rx0a = rx0 & ~3;
        WrA  = (rx1 + 2 - rx0a + 3) & ~3;
        stride = WrA + 4; if ((stride & 31) == 0) stride += 4;
    } else if (lvl == 2) {
        rx0a = rx0 & ~1;
        WrA  = (rx1 + 2 - rx0a + 1) & ~1;
        stride = WrA + 2; if ((stride & 31) == 0) stride += 2;
    } else {
        rx0a = rx0;
        WrA  = rx1 + 2 - rx0;
        stride = WrA | 1;
    }

    // ---- interp prep ONCE (channel-independent) ----
    const int py = (lane < NPP) ? lane / P : 6;
    const int px = (lane < NPP) ? lane - py * P : 6;
    float wta[2][2], wtb[2][2], wtc[2][2], wtd[2][2];
    int   adr[2][2];
    {
        int   y0[2], x0[2];
        float fy[2], hy[2], vy[2], fx[2], hx[2], vx[2];
#pragma unroll
        for (int s = 0; s < 2; ++s) {
            const float yc = y1 + ((float)py + (s ? 0.75f : 0.25f)) * bh;
            vy[s] = (yc > -1.0f && yc < Lf) ? 1.0f : 0.0f;
            const float ycc = fminf(fmaxf(yc, 0.0f), Lm1);
            y0[s] = min((int)ycc, Lm2);
            fy[s] = ycc - (float)y0[s];
            hy[s] = 1.0f - fy[s];

            const float xc = x1 + ((float)px + (s ? 0.75f : 0.25f)) * bw;
            vx[s] = (xc > -1.0f && xc < Lf) ? 1.0f : 0.0f;
            const float xcc = fminf(fmaxf(xc, 0.0f), Lm1);
            x0[s] = min((int)xcc, Lm2);
            fx[s] = xcc - (float)x0[s];
            hx[s] = 1.0f - fx[s];
        }
#pragma unroll
        for (int sy = 0; sy < 2; ++sy)
#pragma unroll
        for (int sx = 0; sx < 2; ++sx) {
            const float w = 0.25f * vy[sy] * vx[sx];
            wta[sy][sx] = w * hy[sy] * hx[sx];
            wtb[sy][sx] = w * hy[sy] * fx[sx];
            wtc[sy][sx] = w * fy[sy] * hx[sx];
            wtd[sy][sx] = w * fy[sy] * fx[sx];
            adr[sy][sx] = (y0[sy] - ry0) * stride - rx0a + x0[sx];
        }
    }

    // ---- staging lane geometry ONCE (pow2 cols-per-row -> rows-per-pass) ----
    // f4: quads per row
    const int qpr  = WrA >> 2;
    const int p2q  = (qpr > 1) ? (32 - __clz(qpr - 1)) : 0;   // qprP2 = 1<<p2q
    const int rp4  = 64 >> p2q;                               // rows per pass
    const int sub4 = lane >> p2q;
    const int cq4  = min((lane & ((1 << p2q) - 1)) << 2, WrA - 4);
    // f2: pairs per row
    const int ppr  = WrA >> 1;
    const int p2p  = (ppr > 1) ? (32 - __clz(ppr - 1)) : 0;
    const int rp2  = 64 >> p2p;
    const int sub2 = lane >> p2p;
    const int cp2  = min((lane & ((1 << p2p) - 1)) << 1, WrA - 2);
    // b32: cols per row
    const int p2c  = (WrA > 1) ? (32 - __clz(WrA - 1)) : 0;
    const int rp1  = 64 >> p2c;
    const int sub1 = lane >> p2c;
    const int cc1  = min(lane & ((1 << p2c) - 1), WrA - 1);

    float* sp = sreg[wy];
    const int c_first = cq * (CHIT * 4) + wy;
    size_t ob = ((size_t)n * NCH + c_first) * NPP + lane;

    for (int it = 0; it < CHIT; ++it) {
        const int c    = c_first + (it << 2);
        const int poff = rfl((b * NCH + c) * LL + ry0 * L + rx0a);  // SALU
        const float* gp = feat + poff;

        // ---- stage region -> LDS (2 row-groups per iter = 2 loads in flight) ----
        if (lvl <= 1) {
            for (int r = 0; r < Hr; r += 2 * rp4) {
                const int rA = min(r + sub4, Hm1);
                const int rB = min(r + rp4 + sub4, Hm1);
                const f4 vA = *(const f4*)(gp + rA * L + cq4);
                const f4 vB = *(const f4*)(gp + rB * L + cq4);
                *(f4*)(sp + rA * stride + cq4) = vA;
                *(f4*)(sp + rB * stride + cq4) = vB;   // tail dup = same data
            }
        } else if (lvl == 2) {
            for (int r = 0; r < Hr; r += 2 * rp2) {
                const int rA = min(r + sub2, Hm1);
                const int rB = min(r + rp2 + sub2, Hm1);
                const f2 vA = *(const f2*)(gp + rA * L + cp2);
                const f2 vB = *(const f2*)(gp + rB * L + cp2);
                *(f2*)(sp + rA * stride + cp2) = vA;
                *(f2*)(sp + rB * stride + cp2) = vB;
            }
        } else {
            for (int r = 0; r < Hr; r += 2 * rp1) {
                const int rA = min(r + sub1, Hm1);
                const int rB = min(r + rp1 + sub1, Hm1);
                const float vA = gp[rA * L + cc1];
                const float vB = gp[rB * L + cc1];
                sp[rA * stride + cc1] = vA;
                sp[rB * stride + cc1] = vB;
            }
        }
        // NO barrier: sreg[wy] is wave-private; per-wave DS ops complete in
        // program order, so iter k's ds_reads finish before iter k+1's writes.

        // ---- interp from LDS (weights + addresses precomputed) ----
        if (lane < NPP) {
            float acc = 0.0f;
#pragma unroll
            for (int sy = 0; sy < 2; ++sy)
#pragma unroll
            for (int sx = 0; sx < 2; ++sx) {
                const int a = adr[sy][sx];
                acc += wta[sy][sx] * sp[a]
                     + wtb[sy][sx] * sp[a + 1]
                     + wtc[sy][sx] * sp[a + stride]
                     + wtd[sy][sx] * sp[a + stride + 1];
            }
            out[ob] = acc;
        }
        ob += (size_t)4 * NPP;
    }
}

extern "C" void kernel_launch(void* const* d_in, const int* in_sizes, int n_in,
                              void* d_out, int out_size, void* d_ws, size_t ws_size,
                              hipStream_t stream) {
    const float* boxes     = (const float*)d_in[0];
    const int*   batch_ids = (const int*)d_in[1];
    const float* g0        = (const float*)d_in[2];
    const float* g1        = (const float*)d_in[3];
    const float* g2        = (const float*)d_in[4];
    const float* g3        = (const float*)d_in[5];
    float* out = (float*)d_out;

    const int N = in_sizes[0] / 4;                 // 512
    dim3 block(64, 4);                             // 4 waves; wave = 4 channels serial
    dim3 grid(NCH / (CHIT * 4), N);                // (16, 512)
    pooler_kernel<<<grid, block, 0, stream>>>(boxes, batch_ids, g0, g1, g2, g3, out);
}

// Round 24
// 51.251 us; speedup vs baseline: 2.2264x; 1.0277x over previous
//
#include <hip/hip_runtime.h>

#define P 7
#define NCH 256
#define NPP 49
#define CHIT 8          // channels per wave (serial) — r24: 4 -> 8
#define LDS_CAP 2048    // worst Hr*stride ~1968 (lvl-0 w'=4..6, h'=128), re-proven r24

typedef float f2 __attribute__((ext_vector_type(2), aligned(8)));
typedef float f4 __attribute__((ext_vector_type(4), aligned(16)));

__device__ __forceinline__ int rfl(int x) { return __builtin_amdgcn_readfirstlane(x); }

__global__ __launch_bounds__(256) void pooler_kernel(
    const float* __restrict__ boxes,
    const int* __restrict__ batch_ids,
    const float* __restrict__ g0, const float* __restrict__ g1,
    const float* __restrict__ g2, const float* __restrict__ g3,
    float* __restrict__ out)
{
    __shared__ __align__(16) float sreg[4][LDS_CAP];   // 32 KB; wave-private rows

    const int n    = blockIdx.y;          // box
    const int cq   = blockIdx.x;          // channel octa-group 0..7
    const int lane = threadIdx.x;         // 0..63
    const int wy   = threadIdx.y;         // wave index

    // ---- box + level (wave-uniform; SGPR via rfl) ----
    const float x1i = boxes[n*4+0], y1i = boxes[n*4+1];
    const float x2i = boxes[n*4+2], y2i = boxes[n*4+3];
    const float area = (x2i - x1i) * (y2i - y1i);
    float lvlf = floorf(4.0f + log2f(sqrtf(area) / 224.0f + 1e-6f));
    lvlf = fminf(fmaxf(lvlf, 2.0f), 5.0f);
    const int lvl = rfl((int)lvlf - 2);   // 0..3

    const float* feat = (lvl==0) ? g0 : (lvl==1) ? g1 : (lvl==2) ? g2 : g3;
    const int    L    = (lvl==0) ? 200 : (lvl==1) ? 100 : (lvl==2) ? 50 : 25;
    const float scale = (lvl==0) ? 0.25f : (lvl==1) ? 0.125f
                      : (lvl==2) ? 0.0625f : 0.03125f;
    const int b  = batch_ids[n];
    const int LL = L * L;

    const float x1 = x1i * scale, y1 = y1i * scale;
    const float bw = fmaxf(x2i*scale - x1, 1.0f) * (1.0f/7.0f);
    const float bh = fmaxf(y2i*scale - y1, 1.0f) * (1.0f/7.0f);
    const float Lf = (float)L, Lm1 = Lf - 1.0f;
    const int   Lm2 = L - 2;

    // ---- region bounds -> SGPRs ----
    const int rx0 = rfl(min((int)fminf(fmaxf(x1 + 0.25f*bw, 0.0f), Lm1), Lm2));
    const int rx1 = rfl(min((int)fminf(fmaxf(x1 + 6.75f*bw, 0.0f), Lm1), Lm2));
    const int ry0 = rfl(min((int)fminf(fmaxf(y1 + 0.25f*bh, 0.0f), Lm1), Lm2));
    const int ry1 = rfl(min((int)fminf(fmaxf(y1 + 6.75f*bh, 0.0f), Lm1), Lm2));
    const int Hr  = ry1 - ry0 + 2;
    const int Hm1 = Hr - 1;

    // ---- level-dependent aligned region layout (all SALU) ----
    int rx0a, WrA, stride;
    if (lvl <= 1) {
        rx0a = rx0 & ~3;
        WrA  = (rx1 + 2 - rx0a + 3) & ~3;
        stride = WrA + 4; if ((stride & 31) == 0) stride += 4;
    } else if (lvl == 2) {
        rx0a = rx0 & ~1;
        WrA  = (rx1 + 2 - rx0a + 1) & ~1;
        stride = WrA + 2; if ((stride & 31) == 0) stride += 2;
    } else {
        rx0a = rx0;
        WrA  = rx1 + 2 - rx0;
        stride = WrA | 1;
    }

    // ---- interp prep ONCE (channel-independent) ----
    const int py = (lane < NPP) ? lane / P : 6;
    const int px = (lane < NPP) ? lane - py * P : 6;
    float wta[2][2], wtb[2][2], wtc[2][2], wtd[2][2];
    int   adr[2][2];
    {
        int   y0[2], x0[2];
        float fy[2], hy[2], vy[2], fx[2], hx[2], vx[2];
#pragma unroll
        for (int s = 0; s < 2; ++s) {
            const float yc = y1 + ((float)py + (s ? 0.75f : 0.25f)) * bh;
            vy[s] = (yc > -1.0f && yc < Lf) ? 1.0f : 0.0f;
            const float ycc = fminf(fmaxf(yc, 0.0f), Lm1);
            y0[s] = min((int)ycc, Lm2);
            fy[s] = ycc - (float)y0[s];
            hy[s] = 1.0f - fy[s];

            const float xc = x1 + ((float)px + (s ? 0.75f : 0.25f)) * bw;
            vx[s] = (xc > -1.0f && xc < Lf) ? 1.0f : 0.0f;
            const float xcc = fminf(fmaxf(xc, 0.0f), Lm1);
            x0[s] = min((int)xcc, Lm2);
            fx[s] = xcc - (float)x0[s];
            hx[s] = 1.0f - fx[s];
        }
#pragma unroll
        for (int sy = 0; sy < 2; ++sy)
#pragma unroll
        for (int sx = 0; sx < 2; ++sx) {
            const float w = 0.25f * vy[sy] * vx[sx];
            wta[sy][sx] = w * hy[sy] * hx[sx];
            wtb[sy][sx] = w * hy[sy] * fx[sx];
            wtc[sy][sx] = w * fy[sy] * hx[sx];
            wtd[sy][sx] = w * fy[sy] * fx[sx];
            adr[sy][sx] = (y0[sy] - ry0) * stride - rx0a + x0[sx];
        }
    }

    // ---- staging lane geometry ONCE (pow2 cols-per-row -> rows-per-pass) ----
    const int qpr  = WrA >> 2;
    const int p2q  = (qpr > 1) ? (32 - __clz(qpr - 1)) : 0;
    const int rp4  = 64 >> p2q;
    const int sub4 = lane >> p2q;
    const int cq4  = min((lane & ((1 << p2q) - 1)) << 2, WrA - 4);
    const int ppr  = WrA >> 1;
    const int p2p  = (ppr > 1) ? (32 - __clz(ppr - 1)) : 0;
    const int rp2  = 64 >> p2p;
    const int sub2 = lane >> p2p;
    const int cp2  = min((lane & ((1 << p2p) - 1)) << 1, WrA - 2);
    const int p2c  = (WrA > 1) ? (32 - __clz(WrA - 1)) : 0;
    const int rp1  = 64 >> p2c;
    const int sub1 = lane >> p2c;
    const int cc1  = min(lane & ((1 << p2c) - 1), WrA - 1);

    float* sp = sreg[wy];
    const int c_first = cq * (CHIT * 4) + wy;
    size_t ob = ((size_t)n * NCH + c_first) * NPP + lane;

    for (int it = 0; it < CHIT; ++it) {
        const int c    = c_first + (it << 2);
        const int poff = rfl((b * NCH + c) * LL + ry0 * L + rx0a);  // SALU
        const float* gp = feat + poff;

        // ---- stage region -> LDS (2 row-groups per iter = 2 loads in flight) ----
        if (lvl <= 1) {
            for (int r = 0; r < Hr; r += 2 * rp4) {
                const int rA = min(r + sub4, Hm1);
                const int rB = min(r + rp4 + sub4, Hm1);
                const f4 vA = *(const f4*)(gp + rA * L + cq4);
                const f4 vB = *(const f4*)(gp + rB * L + cq4);
                *(f4*)(sp + rA * stride + cq4) = vA;
                *(f4*)(sp + rB * stride + cq4) = vB;   // tail dup = same data
            }
        } else if (lvl == 2) {
            for (int r = 0; r < Hr; r += 2 * rp2) {
                const int rA = min(r + sub2, Hm1);
                const int rB = min(r + rp2 + sub2, Hm1);
                const f2 vA = *(const f2*)(gp + rA * L + cp2);
                const f2 vB = *(const f2*)(gp + rB * L + cp2);
                *(f2*)(sp + rA * stride + cp2) = vA;
                *(f2*)(sp + rB * stride + cp2) = vB;
            }
        } else {
            for (int r = 0; r < Hr; r += 2 * rp1) {
                const int rA = min(r + sub1, Hm1);
                const int rB = min(r + rp1 + sub1, Hm1);
                const float vA = gp[rA * L + cc1];
                const float vB = gp[rB * L + cc1];
                sp[rA * stride + cc1] = vA;
                sp[rB * stride + cc1] = vB;
            }
        }
        // NO barrier: sreg[wy] is wave-private; per-wave DS ops complete in
        // program order, so iter k's ds_reads finish before iter k+1's writes.

        // ---- interp from LDS (weights + addresses precomputed) ----
        if (lane < NPP) {
            float acc = 0.0f;
#pragma unroll
            for (int sy = 0; sy < 2; ++sy)
#pragma unroll
            for (int sx = 0; sx < 2; ++sx) {
                const int a = adr[sy][sx];
                acc += wta[sy][sx] * sp[a]
                     + wtb[sy][sx] * sp[a + 1]
                     + wtc[sy][sx] * sp[a + stride]
                     + wtd[sy][sx] * sp[a + stride + 1];
            }
            out[ob] = acc;
        }
        ob += (size_t)4 * NPP;
    }
}

extern "C" void kernel_launch(void* const* d_in, const int* in_sizes, int n_in,
                              void* d_out, int out_size, void* d_ws, size_t ws_size,
                              hipStream_t stream) {
    const float* boxes     = (const float*)d_in[0];
    const int*   batch_ids = (const int*)d_in[1];
    const float* g0        = (const float*)d_in[2];
    const float* g1        = (const float*)d_in[3];
    const float* g2        = (const float*)d_in[4];
    const float* g3        = (const float*)d_in[5];
    float* out = (float*)d_out;

    const int N = in_sizes[0] / 4;                 // 512
    dim3 block(64, 4);                             // 4 waves; wave = 8 channels serial
    dim3 grid(NCH / (CHIT * 4), N);                // (8, 512)
    pooler_kernel<<<grid, block, 0, stream>>>(boxes, batch_ids, g0, g1, g2, g3, out);
}

// Round 26
// 50.410 us; speedup vs baseline: 2.2635x; 1.0167x over previous
//
#include <hip/hip_runtime.h>

#define P 7
#define NCH 256
#define NPP 49
#define CHIT 8          // channels per wave (serial)
#define LDS_CAP 1440    // f4 path gated by exact Hr*stride<=CAP check (r26);
                        // f2 fallback worst case = 1386 (span=8, Hr<=99, stride<=14)

typedef float f2 __attribute__((ext_vector_type(2), aligned(8)));
typedef float f4 __attribute__((ext_vector_type(4), aligned(16)));

__device__ __forceinline__ int rfl(int x) { return __builtin_amdgcn_readfirstlane(x); }

__global__ __launch_bounds__(256) void pooler_kernel(
    const float* __restrict__ boxes,
    const int* __restrict__ batch_ids,
    const float* __restrict__ g0, const float* __restrict__ g1,
    const float* __restrict__ g2, const float* __restrict__ g3,
    float* __restrict__ out)
{
    __shared__ __align__(16) float sreg[4][LDS_CAP];   // 23 KB -> 7 blocks/CU

    const int n    = blockIdx.y;          // box
    const int cq   = blockIdx.x;          // channel octa-group 0..7
    const int lane = threadIdx.x;         // 0..63
    const int wy   = threadIdx.y;         // wave index

    // ---- box + level (wave-uniform; SGPR via rfl) ----
    const float x1i = boxes[n*4+0], y1i = boxes[n*4+1];
    const float x2i = boxes[n*4+2], y2i = boxes[n*4+3];
    const float area = (x2i - x1i) * (y2i - y1i);
    float lvlf = floorf(4.0f + log2f(sqrtf(area) / 224.0f + 1e-6f));
    lvlf = fminf(fmaxf(lvlf, 2.0f), 5.0f);
    const int lvl = rfl((int)lvlf - 2);   // 0..3

    const float* feat = (lvl==0) ? g0 : (lvl==1) ? g1 : (lvl==2) ? g2 : g3;
    const int    L    = (lvl==0) ? 200 : (lvl==1) ? 100 : (lvl==2) ? 50 : 25;
    const float scale = (lvl==0) ? 0.25f : (lvl==1) ? 0.125f
                      : (lvl==2) ? 0.0625f : 0.03125f;
    const int b  = batch_ids[n];
    const int LL = L * L;

    const float x1 = x1i * scale, y1 = y1i * scale;
    const float bw = fmaxf(x2i*scale - x1, 1.0f) * (1.0f/7.0f);
    const float bh = fmaxf(y2i*scale - y1, 1.0f) * (1.0f/7.0f);
    const float Lf = (float)L, Lm1 = Lf - 1.0f;
    const int   Lm2 = L - 2;

    // ---- region bounds -> SGPRs ----
    const int rx0 = rfl(min((int)fminf(fmaxf(x1 + 0.25f*bw, 0.0f), Lm1), Lm2));
    const int rx1 = rfl(min((int)fminf(fmaxf(x1 + 6.75f*bw, 0.0f), Lm1), Lm2));
    const int ry0 = rfl(min((int)fminf(fmaxf(y1 + 0.25f*bh, 0.0f), Lm1), Lm2));
    const int ry1 = rfl(min((int)fminf(fmaxf(y1 + 6.75f*bh, 0.0f), Lm1), Lm2));
    const int Hr  = ry1 - ry0 + 2;
    const int Hm1 = Hr - 1;

    // ---- width-class + aligned layout (all SALU) ----
    // path 0: f4 — ONLY if wide enough AND Hr*stride fits LDS_CAP (r26 fix)
    // path 1: f2 (L%2==0 for lvl<=2), stride%4==2 preferred
    // path 2: b32 (lvl==3), stride odd
    int path, rx0a, WrA, stride;
    if (lvl <= 1) {
        const int a4 = rx0 & ~3;
        const int W4 = (rx1 + 2 - a4 + 3) & ~3;
        const int s4 = ((W4 & 7) == 4) ? W4 : W4 + 4;
        if (W4 >= 16 && Hr * s4 <= LDS_CAP) {
            path = 0; rx0a = a4; WrA = W4; stride = s4;
        } else {
            path = 1; rx0a = rx0 & ~1;
            WrA = (rx1 + 2 - rx0a + 1) & ~1;
            stride = ((WrA & 3) == 2) ? WrA : WrA + 2;
        }
    } else if (lvl == 2) {
        path = 1; rx0a = rx0 & ~1;
        WrA = (rx1 + 2 - rx0a + 1) & ~1;
        stride = ((WrA & 3) == 2) ? WrA : WrA + 2;
    } else {
        path = 2; rx0a = rx0; WrA = rx1 + 2 - rx0;
        stride = WrA | 1;
    }
    if (Hr * stride > LDS_CAP) stride = WrA;   // provably never taken; safety

    // ---- interp prep ONCE (channel-independent) ----
    const int py = (lane < NPP) ? lane / P : 6;
    const int px = (lane < NPP) ? lane - py * P : 6;
    float wta[2][2], wtb[2][2], wtc[2][2], wtd[2][2];
    int   adr[2][2];
    {
        int   y0[2], x0[2];
        float fy[2], hy[2], vy[2], fx[2], hx[2], vx[2];
#pragma unroll
        for (int s = 0; s < 2; ++s) {
            const float yc = y1 + ((float)py + (s ? 0.75f : 0.25f)) * bh;
            vy[s] = (yc > -1.0f && yc < Lf) ? 1.0f : 0.0f;
            const float ycc = fminf(fmaxf(yc, 0.0f), Lm1);
            y0[s] = min((int)ycc, Lm2);
            fy[s] = ycc - (float)y0[s];
            hy[s] = 1.0f - fy[s];

            const float xc = x1 + ((float)px + (s ? 0.75f : 0.25f)) * bw;
            vx[s] = (xc > -1.0f && xc < Lf) ? 1.0f : 0.0f;
            const float xcc = fminf(fmaxf(xc, 0.0f), Lm1);
            x0[s] = min((int)xcc, Lm2);
            fx[s] = xcc - (float)x0[s];
            hx[s] = 1.0f - fx[s];
        }
#pragma unroll
        for (int sy = 0; sy < 2; ++sy)
#pragma unroll
        for (int sx = 0; sx < 2; ++sx) {
            const float w = 0.25f * vy[sy] * vx[sx];
            wta[sy][sx] = w * hy[sy] * hx[sx];
            wtb[sy][sx] = w * hy[sy] * fx[sx];
            wtc[sy][sx] = w * fy[sy] * hx[sx];
            wtd[sy][sx] = w * fy[sy] * fx[sx];
            adr[sy][sx] = (y0[sy] - ry0) * stride - rx0a + x0[sx];
        }
    }

    // ---- staging lane geometry ONCE (pow2 cols-per-row -> rows-per-pass) ----
    const int qpr  = WrA >> 2;
    const int p2q  = (qpr > 1) ? (32 - __clz(qpr - 1)) : 0;
    const int rp4  = 64 >> p2q;
    const int sub4 = lane >> p2q;
    const int cq4  = min((lane & ((1 << p2q) - 1)) << 2, WrA - 4);
    const int ppr  = WrA >> 1;
    const int p2p  = (ppr > 1) ? (32 - __clz(ppr - 1)) : 0;
    const int rp2  = 64 >> p2p;
    const int sub2 = lane >> p2p;
    const int cp2  = min((lane & ((1 << p2p) - 1)) << 1, WrA - 2);
    const int p2c  = (WrA > 1) ? (32 - __clz(WrA - 1)) : 0;
    const int rp1  = 64 >> p2c;
    const int sub1 = lane >> p2c;
    const int cc1  = min(lane & ((1 << p2c) - 1), WrA - 1);

    float* sp = sreg[wy];
    const int c_first = cq * (CHIT * 4) + wy;
    size_t ob = ((size_t)n * NCH + c_first) * NPP + lane;

    for (int it = 0; it < CHIT; ++it) {
        const int c    = c_first + (it << 2);
        const int poff = rfl((b * NCH + c) * LL + ry0 * L + rx0a);  // SALU
        const float* gp = feat + poff;

        // ---- stage region -> LDS (2 row-groups per iter = 2 loads in flight) ----
        if (path == 0) {
            for (int r = 0; r < Hr; r += 2 * rp4) {
                const int rA = min(r + sub4, Hm1);
                const int rB = min(r + rp4 + sub4, Hm1);
                const f4 vA = *(const f4*)(gp + rA * L + cq4);
                const f4 vB = *(const f4*)(gp + rB * L + cq4);
                *(f4*)(sp + rA * stride + cq4) = vA;
                *(f4*)(sp + rB * stride + cq4) = vB;   // tail dup = same data
            }
        } else if (path == 1) {
            for (int r = 0; r < Hr; r += 2 * rp2) {
                const int rA = min(r + sub2, Hm1);
                const int rB = min(r + rp2 + sub2, Hm1);
                const f2 vA = *(const f2*)(gp + rA * L + cp2);
                const f2 vB = *(const f2*)(gp + rB * L + cp2);
                *(f2*)(sp + rA * stride + cp2) = vA;
                *(f2*)(sp + rB * stride + cp2) = vB;
            }
        } else {
            for (int r = 0; r < Hr; r += 2 * rp1) {
                const int rA = min(r + sub1, Hm1);
                const int rB = min(r + rp1 + sub1, Hm1);
                const float vA = gp[rA * L + cc1];
                const float vB = gp[rB * L + cc1];
                sp[rA * stride + cc1] = vA;
                sp[rB * stride + cc1] = vB;
            }
        }
        // NO barrier: sreg[wy] is wave-private; per-wave DS ops complete in
        // program order, so iter k's ds_reads finish before iter k+1's writes.

        // ---- interp from LDS (weights + addresses precomputed) ----
        if (lane < NPP) {
            float acc = 0.0f;
#pragma unroll
            for (int sy = 0; sy < 2; ++sy)
#pragma unroll
            for (int sx = 0; sx < 2; ++sx) {
                const int a = adr[sy][sx];
                acc += wta[sy][sx] * sp[a]
                     + wtb[sy][sx] * sp[a + 1]
                     + wtc[sy][sx] * sp[a + stride]
                     + wtd[sy][sx] * sp[a + stride + 1];
            }
            out[ob] = acc;
        }
        ob += (size_t)4 * NPP;
    }
}

extern "C" void kernel_launch(void* const* d_in, const int* in_sizes, int n_in,
                              void* d_out, int out_size, void* d_ws, size_t ws_size,
                              hipStream_t stream) {
    const float* boxes     = (const float*)d_in[0];
    const int*   batch_ids = (const int*)d_in[1];
    const float* g0        = (const float*)d_in[2];
    const float* g1        = (const float*)d_in[3];
    const float* g2        = (const float*)d_in[4];
    const float* g3        = (const float*)d_in[5];
    float* out = (float*)d_out;

    const int N = in_sizes[0] / 4;                 // 512
    dim3 block(64, 4);                             // 4 waves; wave = 8 channels serial
    dim3 grid(NCH / (CHIT * 4), N);                // (8, 512)
    pooler_kernel<<<grid, block, 0, stream>>>(boxes, batch_ids, g0, g1, g2, g3, out);
}

// Round 28
// 49.647 us; speedup vs baseline: 2.2983x; 1.0154x over previous
//
#include <hip/hip_runtime.h>

#define P 7
#define NCH 256
#define NPP 49
#define CHIT 8          // channels per wave (serial)
#define LDS_CAP 1440    // f4 path gated by exact Hr*stride<=CAP check (r26);
                        // f2 fallback worst case = 1386 (span=8, Hr<=99, stride<=14)

typedef float f2 __attribute__((ext_vector_type(2), aligned(8)));
typedef float f4 __attribute__((ext_vector_type(4), aligned(16)));

__device__ __forceinline__ int rfl(int x) { return __builtin_amdgcn_readfirstlane(x); }

__global__ __launch_bounds__(256) void pooler_kernel(
    const float* __restrict__ boxes,
    const int* __restrict__ batch_ids,
    const float* __restrict__ g0, const float* __restrict__ g1,
    const float* __restrict__ g2, const float* __restrict__ g3,
    float* __restrict__ out)
{
    __shared__ __align__(16) float sreg[4][LDS_CAP];   // 23 KB -> 7 blocks/CU

    const int n    = blockIdx.y;          // box
    const int cq   = blockIdx.x;          // channel octa-group 0..7
    const int lane = threadIdx.x;         // 0..63
    const int wy   = threadIdx.y;         // wave index

    // ---- box + level (wave-uniform; SGPR via rfl) ----
    const float x1i = boxes[n*4+0], y1i = boxes[n*4+1];
    const float x2i = boxes[n*4+2], y2i = boxes[n*4+3];
    const float area = (x2i - x1i) * (y2i - y1i);
    float lvlf = floorf(4.0f + log2f(sqrtf(area) / 224.0f + 1e-6f));
    lvlf = fminf(fmaxf(lvlf, 2.0f), 5.0f);
    const int lvl = rfl((int)lvlf - 2);   // 0..3

    const float* feat = (lvl==0) ? g0 : (lvl==1) ? g1 : (lvl==2) ? g2 : g3;
    const int    L    = (lvl==0) ? 200 : (lvl==1) ? 100 : (lvl==2) ? 50 : 25;
    const float scale = (lvl==0) ? 0.25f : (lvl==1) ? 0.125f
                      : (lvl==2) ? 0.0625f : 0.03125f;
    const int b  = batch_ids[n];
    const int LL = L * L;

    const float x1 = x1i * scale, y1 = y1i * scale;
    const float bw = fmaxf(x2i*scale - x1, 1.0f) * (1.0f/7.0f);
    const float bh = fmaxf(y2i*scale - y1, 1.0f) * (1.0f/7.0f);
    const float Lf = (float)L, Lm1 = Lf - 1.0f;
    const int   Lm2 = L - 2;

    // ---- region bounds -> SGPRs ----
    const int rx0 = rfl(min((int)fminf(fmaxf(x1 + 0.25f*bw, 0.0f), Lm1), Lm2));
    const int rx1 = rfl(min((int)fminf(fmaxf(x1 + 6.75f*bw, 0.0f), Lm1), Lm2));
    const int ry0 = rfl(min((int)fminf(fmaxf(y1 + 0.25f*bh, 0.0f), Lm1), Lm2));
    const int ry1 = rfl(min((int)fminf(fmaxf(y1 + 6.75f*bh, 0.0f), Lm1), Lm2));
    const int Hr  = ry1 - ry0 + 2;
    const int Hm1 = Hr - 1;

    // ---- width-class + aligned layout (all SALU) ----
    // path 0: f4 — ONLY if wide enough AND Hr*stride fits LDS_CAP (r26 fix)
    // path 1: f2 (L%2==0 for lvl<=2), stride%4==2 preferred
    // path 2: b32 (lvl==3), stride odd
    int path, rx0a, WrA, stride;
    if (lvl <= 1) {
        const int a4 = rx0 & ~3;
        const int W4 = (rx1 + 2 - a4 + 3) & ~3;
        const int s4 = ((W4 & 7) == 4) ? W4 : W4 + 4;
        if (W4 >= 16 && Hr * s4 <= LDS_CAP) {
            path = 0; rx0a = a4; WrA = W4; stride = s4;
        } else {
            path = 1; rx0a = rx0 & ~1;
            WrA = (rx1 + 2 - rx0a + 1) & ~1;
            stride = ((WrA & 3) == 2) ? WrA : WrA + 2;
        }
    } else if (lvl == 2) {
        path = 1; rx0a = rx0 & ~1;
        WrA = (rx1 + 2 - rx0a + 1) & ~1;
        stride = ((WrA & 3) == 2) ? WrA : WrA + 2;
    } else {
        path = 2; rx0a = rx0; WrA = rx1 + 2 - rx0;
        stride = WrA | 1;
    }
    if (Hr * stride > LDS_CAP) stride = WrA;   // provably never taken; safety

    // ---- interp prep ONCE (channel-independent) ----
    const int py = (lane < NPP) ? lane / P : 6;
    const int px = (lane < NPP) ? lane - py * P : 6;
    float wta[2][2], wtb[2][2], wtc[2][2], wtd[2][2];
    int   adr[2][2];
    {
        int   y0[2], x0[2];
        float fy[2], hy[2], vy[2], fx[2], hx[2], vx[2];
#pragma unroll
        for (int s = 0; s < 2; ++s) {
            const float yc = y1 + ((float)py + (s ? 0.75f : 0.25f)) * bh;
            vy[s] = (yc > -1.0f && yc < Lf) ? 1.0f : 0.0f;
            const float ycc = fminf(fmaxf(yc, 0.0f), Lm1);
            y0[s] = min((int)ycc, Lm2);
            fy[s] = ycc - (float)y0[s];
            hy[s] = 1.0f - fy[s];

            const float xc = x1 + ((float)px + (s ? 0.75f : 0.25f)) * bw;
            vx[s] = (xc > -1.0f && xc < Lf) ? 1.0f : 0.0f;
            const float xcc = fminf(fmaxf(xc, 0.0f), Lm1);
            x0[s] = min((int)xcc, Lm2);
            fx[s] = xcc - (float)x0[s];
            hx[s] = 1.0f - fx[s];
        }
#pragma unroll
        for (int sy = 0; sy < 2; ++sy)
#pragma unroll
        for (int sx = 0; sx < 2; ++sx) {
            const float w = 0.25f * vy[sy] * vx[sx];
            wta[sy][sx] = w * hy[sy] * hx[sx];
            wtb[sy][sx] = w * hy[sy] * fx[sx];
            wtc[sy][sx] = w * fy[sy] * hx[sx];
            wtd[sy][sx] = w * fy[sy] * fx[sx];
            adr[sy][sx] = (y0[sy] - ry0) * stride - rx0a + x0[sx];
        }
    }

    // ---- staging lane geometry ONCE (pow2 cols-per-row -> rows-per-pass) ----
    const int qpr  = WrA >> 2;
    const int p2q  = (qpr > 1) ? (32 - __clz(qpr - 1)) : 0;
    const int rp4  = 64 >> p2q;
    const int sub4 = lane >> p2q;
    const int cq4  = min((lane & ((1 << p2q) - 1)) << 2, WrA - 4);
    const int ppr  = WrA >> 1;
    const int p2p  = (ppr > 1) ? (32 - __clz(ppr - 1)) : 0;
    const int rp2  = 64 >> p2p;
    const int sub2 = lane >> p2p;
    const int cp2  = min((lane & ((1 << p2p) - 1)) << 1, WrA - 2);
    const int p2c  = (WrA > 1) ? (32 - __clz(WrA - 1)) : 0;
    const int rp1  = 64 >> p2c;
    const int sub1 = lane >> p2c;
    const int cc1  = min(lane & ((1 << p2c) - 1), WrA - 1);

    float* sp = sreg[wy];
    const int c_first = cq * (CHIT * 4) + wy;
    size_t ob = ((size_t)n * NCH + c_first) * NPP + lane;

    for (int it = 0; it < CHIT; ++it) {
        const int c    = c_first + (it << 2);
        const int poff = rfl((b * NCH + c) * LL + ry0 * L + rx0a);  // SALU
        const float* gp = feat + poff;

        // ---- stage region -> LDS (2 row-groups per iter = 2 loads in flight) ----
        if (path == 0) {
            for (int r = 0; r < Hr; r += 2 * rp4) {
                const int rA = min(r + sub4, Hm1);
                const int rB = min(r + rp4 + sub4, Hm1);
                const f4 vA = *(const f4*)(gp + rA * L + cq4);
                const f4 vB = *(const f4*)(gp + rB * L + cq4);
                *(f4*)(sp + rA * stride + cq4) = vA;
                *(f4*)(sp + rB * stride + cq4) = vB;   // tail dup = same data
            }
        } else if (path == 1) {
            for (int r = 0; r < Hr; r += 2 * rp2) {
                const int rA = min(r + sub2, Hm1);
                const int rB = min(r + rp2 + sub2, Hm1);
                const f2 vA = *(const f2*)(gp + rA * L + cp2);
                const f2 vB = *(const f2*)(gp + rB * L + cp2);
                *(f2*)(sp + rA * stride + cp2) = vA;
                *(f2*)(sp + rB * stride + cp2) = vB;
            }
        } else {
            for (int r = 0; r < Hr; r += 2 * rp1) {
                const int rA = min(r + sub1, Hm1);
                const int rB = min(r + rp1 + sub1, Hm1);
                const float vA = gp[rA * L + cc1];
                const float vB = gp[rB * L + cc1];
                sp[rA * stride + cc1] = vA;
                sp[rB * stride + cc1] = vB;
            }
        }
        // NO barrier: sreg[wy] is wave-private; per-wave DS ops complete in
        // program order, so iter k's ds_reads finish before iter k+1's writes.

        // ---- interp from LDS (weights + addresses precomputed) ----
        if (lane < NPP) {
            float acc = 0.0f;
#pragma unroll
            for (int sy = 0; sy < 2; ++sy)
#pragma unroll
            for (int sx = 0; sx < 2; ++sx) {
                const int a = adr[sy][sx];
                acc += wta[sy][sx] * sp[a]
                     + wtb[sy][sx] * sp[a + 1]
                     + wtc[sy][sx] * sp[a + stride]
                     + wtd[sy][sx] * sp[a + stride + 1];
            }
            __builtin_nontemporal_store(acc, &out[ob]);   // out never re-read
        }
        ob += (size_t)4 * NPP;
    }
}

extern "C" void kernel_launch(void* const* d_in, const int* in_sizes, int n_in,
                              void* d_out, int out_size, void* d_ws, size_t ws_size,
                              hipStream_t stream) {
    const float* boxes     = (const float*)d_in[0];
    const int*   batch_ids = (const int*)d_in[1];
    const float* g0        = (const float*)d_in[2];
    const float* g1        = (const float*)d_in[3];
    const float* g2        = (const float*)d_in[4];
    const float* g3        = (const float*)d_in[5];
    float* out = (float*)d_out;

    const int N = in_sizes[0] / 4;                 // 512
    dim3 block(64, 4);                             // 4 waves; wave = 8 channels serial
    dim3 grid(NCH / (CHIT * 4), N);                // (8, 512)
    pooler_kernel<<<grid, block, 0, stream>>>(boxes, batch_ids, g0, g1, g2, g3, out);
}

// Round 29
// 48.883 us; speedup vs baseline: 2.3342x; 1.0156x over previous
//
#include <hip/hip_runtime.h>

#define P 7
#define NCH 256
#define NPP 49
#define CHIT 8          // channels per wave (serial)
#define LDS_CAP 1280    // r29: re-derived worst padded-f2 = 1128 (w'<=2, h'<=200);
                        // f4 gated by exact Hr*s4<=CAP; 20KB/block -> 8 blocks/CU

typedef float f2 __attribute__((ext_vector_type(2), aligned(8)));
typedef float f4 __attribute__((ext_vector_type(4), aligned(16)));

__device__ __forceinline__ int rfl(int x) { return __builtin_amdgcn_readfirstlane(x); }

__global__ __launch_bounds__(256) void pooler_kernel(
    const float* __restrict__ boxes,
    const int* __restrict__ batch_ids,
    const float* __restrict__ g0, const float* __restrict__ g1,
    const float* __restrict__ g2, const float* __restrict__ g3,
    float* __restrict__ out)
{
    __shared__ __align__(16) float sreg[4][LDS_CAP];   // 20 KB -> 8 blocks/CU

    const int n    = blockIdx.y;          // box
    const int cq   = blockIdx.x;          // channel octa-group 0..7
    const int lane = threadIdx.x;         // 0..63
    const int wy   = threadIdx.y;         // wave index

    // ---- box + level (wave-uniform; SGPR via rfl) ----
    const float x1i = boxes[n*4+0], y1i = boxes[n*4+1];
    const float x2i = boxes[n*4+2], y2i = boxes[n*4+3];
    const float area = (x2i - x1i) * (y2i - y1i);
    float lvlf = floorf(4.0f + log2f(sqrtf(area) / 224.0f + 1e-6f));
    lvlf = fminf(fmaxf(lvlf, 2.0f), 5.0f);
    const int lvl = rfl((int)lvlf - 2);   // 0..3

    const float* feat = (lvl==0) ? g0 : (lvl==1) ? g1 : (lvl==2) ? g2 : g3;
    const int    L    = (lvl==0) ? 200 : (lvl==1) ? 100 : (lvl==2) ? 50 : 25;
    const float scale = (lvl==0) ? 0.25f : (lvl==1) ? 0.125f
                      : (lvl==2) ? 0.0625f : 0.03125f;
    const int b  = batch_ids[n];
    const int LL = L * L;

    const float x1 = x1i * scale, y1 = y1i * scale;
    const float bw = fmaxf(x2i*scale - x1, 1.0f) * (1.0f/7.0f);
    const float bh = fmaxf(y2i*scale - y1, 1.0f) * (1.0f/7.0f);
    const float Lf = (float)L, Lm1 = Lf - 1.0f;
    const int   Lm2 = L - 2;

    // ---- region bounds -> SGPRs ----
    const int rx0 = rfl(min((int)fminf(fmaxf(x1 + 0.25f*bw, 0.0f), Lm1), Lm2));
    const int rx1 = rfl(min((int)fminf(fmaxf(x1 + 6.75f*bw, 0.0f), Lm1), Lm2));
    const int ry0 = rfl(min((int)fminf(fmaxf(y1 + 0.25f*bh, 0.0f), Lm1), Lm2));
    const int ry1 = rfl(min((int)fminf(fmaxf(y1 + 6.75f*bh, 0.0f), Lm1), Lm2));
    const int Hr  = ry1 - ry0 + 2;
    const int Hm1 = Hr - 1;

    // ---- width-class + aligned layout (all SALU) ----
    // path 0: f4 — only if wide enough AND Hr*stride fits LDS_CAP
    // path 1: f2 (L%2==0 for lvl<=2), stride%4==2 preferred
    // path 2: b32 (lvl==3), stride odd
    int path, rx0a, WrA, stride;
    if (lvl <= 1) {
        const int a4 = rx0 & ~3;
        const int W4 = (rx1 + 2 - a4 + 3) & ~3;
        const int s4 = ((W4 & 7) == 4) ? W4 : W4 + 4;
        if (W4 >= 16 && Hr * s4 <= LDS_CAP) {
            path = 0; rx0a = a4; WrA = W4; stride = s4;
        } else {
            path = 1; rx0a = rx0 & ~1;
            WrA = (rx1 + 2 - rx0a + 1) & ~1;
            stride = ((WrA & 3) == 2) ? WrA : WrA + 2;
        }
    } else if (lvl == 2) {
        path = 1; rx0a = rx0 & ~1;
        WrA = (rx1 + 2 - rx0a + 1) & ~1;
        stride = ((WrA & 3) == 2) ? WrA : WrA + 2;
    } else {
        path = 2; rx0a = rx0; WrA = rx1 + 2 - rx0;
        stride = WrA | 1;
    }
    if (Hr * stride > LDS_CAP) stride = WrA;   // safety net (near-never taken)

    // ---- interp prep ONCE (channel-independent) ----
    const int py = (lane < NPP) ? lane / P : 6;
    const int px = (lane < NPP) ? lane - py * P : 6;
    float wta[2][2], wtb[2][2], wtc[2][2], wtd[2][2];
    int   adr[2][2];
    {
        int   y0[2], x0[2];
        float fy[2], hy[2], vy[2], fx[2], hx[2], vx[2];
#pragma unroll
        for (int s = 0; s < 2; ++s) {
            const float yc = y1 + ((float)py + (s ? 0.75f : 0.25f)) * bh;
            vy[s] = (yc > -1.0f && yc < Lf) ? 1.0f : 0.0f;
            const float ycc = fminf(fmaxf(yc, 0.0f), Lm1);
            y0[s] = min((int)ycc, Lm2);
            fy[s] = ycc - (float)y0[s];
            hy[s] = 1.0f - fy[s];

            const float xc = x1 + ((float)px + (s ? 0.75f : 0.25f)) * bw;
            vx[s] = (xc > -1.0f && xc < Lf) ? 1.0f : 0.0f;
            const float xcc = fminf(fmaxf(xc, 0.0f), Lm1);
            x0[s] = min((int)xcc, Lm2);
            fx[s] = xcc - (float)x0[s];
            hx[s] = 1.0f - fx[s];
        }
#pragma unroll
        for (int sy = 0; sy < 2; ++sy)
#pragma unroll
        for (int sx = 0; sx < 2; ++sx) {
            const float w = 0.25f * vy[sy] * vx[sx];
            wta[sy][sx] = w * hy[sy] * hx[sx];
            wtb[sy][sx] = w * hy[sy] * fx[sx];
            wtc[sy][sx] = w * fy[sy] * hx[sx];
            wtd[sy][sx] = w * fy[sy] * fx[sx];
            adr[sy][sx] = (y0[sy] - ry0) * stride - rx0a + x0[sx];
        }
    }

    // ---- staging lane geometry ONCE (pow2 cols-per-row -> rows-per-pass) ----
    const int qpr  = WrA >> 2;
    const int p2q  = (qpr > 1) ? (32 - __clz(qpr - 1)) : 0;
    const int rp4  = 64 >> p2q;
    const int sub4 = lane >> p2q;
    const int cq4  = min((lane & ((1 << p2q) - 1)) << 2, WrA - 4);
    const int ppr  = WrA >> 1;
    const int p2p  = (ppr > 1) ? (32 - __clz(ppr - 1)) : 0;
    const int rp2  = 64 >> p2p;
    const int sub2 = lane >> p2p;
    const int cp2  = min((lane & ((1 << p2p) - 1)) << 1, WrA - 2);
    const int p2c  = (WrA > 1) ? (32 - __clz(WrA - 1)) : 0;
    const int rp1  = 64 >> p2c;
    const int sub1 = lane >> p2c;
    const int cc1  = min(lane & ((1 << p2c) - 1), WrA - 1);

    float* sp = sreg[wy];
    const int c_first = cq * (CHIT * 4) + wy;
    size_t ob = ((size_t)n * NCH + c_first) * NPP + lane;

    for (int it = 0; it < CHIT; ++it) {
        const int c    = c_first + (it << 2);
        const int poff = rfl((b * NCH + c) * LL + ry0 * L + rx0a);  // SALU
        const float* gp = feat + poff;

        // ---- stage region -> LDS (2 row-groups per iter = 2 loads in flight) ----
        if (path == 0) {
            for (int r = 0; r < Hr; r += 2 * rp4) {
                const int rA = min(r + sub4, Hm1);
                const int rB = min(r + rp4 + sub4, Hm1);
                const f4 vA = *(const f4*)(gp + rA * L + cq4);
                const f4 vB = *(const f4*)(gp + rB * L + cq4);
                *(f4*)(sp + rA * stride + cq4) = vA;
                *(f4*)(sp + rB * stride + cq4) = vB;   // tail dup = same data
            }
        } else if (path == 1) {
            for (int r = 0; r < Hr; r += 2 * rp2) {
                const int rA = min(r + sub2, Hm1);
                const int rB = min(r + rp2 + sub2, Hm1);
                const f2 vA = *(const f2*)(gp + rA * L + cp2);
                const f2 vB = *(const f2*)(gp + rB * L + cp2);
                *(f2*)(sp + rA * stride + cp2) = vA;
                *(f2*)(sp + rB * stride + cp2) = vB;
            }
        } else {
            for (int r = 0; r < Hr; r += 2 * rp1) {
                const int rA = min(r + sub1, Hm1);
                const int rB = min(r + rp1 + sub1, Hm1);
                const float vA = gp[rA * L + cc1];
                const float vB = gp[rB * L + cc1];
                sp[rA * stride + cc1] = vA;
                sp[rB * stride + cc1] = vB;
            }
        }
        // NO barrier: sreg[wy] is wave-private; per-wave DS ops complete in
        // program order, so iter k's ds_reads finish before iter k+1's writes.

        // ---- interp from LDS (weights + addresses precomputed) ----
        if (lane < NPP) {
            float acc = 0.0f;
#pragma unroll
            for (int sy = 0; sy < 2; ++sy)
#pragma unroll
            for (int sx = 0; sx < 2; ++sx) {
                const int a = adr[sy][sx];
                acc += wta[sy][sx] * sp[a]
                     + wtb[sy][sx] * sp[a + 1]
                     + wtc[sy][sx] * sp[a + stride]
                     + wtd[sy][sx] * sp[a + stride + 1];
            }
            __builtin_nontemporal_store(acc, &out[ob]);   // out never re-read
        }
        ob += (size_t)4 * NPP;
    }
}

extern "C" void kernel_launch(void* const* d_in, const int* in_sizes, int n_in,
                              void* d_out, int out_size, void* d_ws, size_t ws_size,
                              hipStream_t stream) {
    const float* boxes     = (const float*)d_in[0];
    const int*   batch_ids = (const int*)d_in[1];
    const float* g0        = (const float*)d_in[2];
    const float* g1        = (const float*)d_in[3];
    const float* g2        = (const float*)d_in[4];
    const float* g3        = (const float*)d_in[5];
    float* out = (float*)d_out;

    const int N = in_sizes[0] / 4;                 // 512
    dim3 block(64, 4);                             // 4 waves; wave = 8 channels serial
    dim3 grid(NCH / (CHIT * 4), N);                // (8, 512)
    pooler_kernel<<<grid, block, 0, stream>>>(boxes, batch_ids, g0, g1, g2, g3, out);
}

// Round 30
// 48.052 us; speedup vs baseline: 2.3746x; 1.0173x over previous
//
#include <hip/hip_runtime.h>

#define P 7
#define NCH 256
#define NPP 49
#define CHIT 8          // channels per wave (serial, consecutive)
#define LDS_CAP 1280    // worst padded-f2 = 1128 (w'<=2, h'<=200); f4 gated exactly

typedef float f2 __attribute__((ext_vector_type(2), aligned(8)));
typedef float f4 __attribute__((ext_vector_type(4), aligned(16)));

__device__ __forceinline__ int rfl(int x) { return __builtin_amdgcn_readfirstlane(x); }

__global__ __launch_bounds__(64) void pooler_kernel(
    const float* __restrict__ boxes,
    const int* __restrict__ batch_ids,
    const float* __restrict__ g0, const float* __restrict__ g1,
    const float* __restrict__ g2, const float* __restrict__ g3,
    float* __restrict__ out)
{
    __shared__ __align__(16) float sreg[LDS_CAP];   // 5 KB -> 32 blocks(waves)/CU

    const int n    = blockIdx.y;          // box
    const int cq   = blockIdx.x;          // channel group 0..31 (8 channels each)
    const int lane = threadIdx.x;         // 0..63

    // ---- box + level (wave-uniform; SGPR via rfl) ----
    const float x1i = boxes[n*4+0], y1i = boxes[n*4+1];
    const float x2i = boxes[n*4+2], y2i = boxes[n*4+3];
    const float area = (x2i - x1i) * (y2i - y1i);
    float lvlf = floorf(4.0f + log2f(sqrtf(area) / 224.0f + 1e-6f));
    lvlf = fminf(fmaxf(lvlf, 2.0f), 5.0f);
    const int lvl = rfl((int)lvlf - 2);   // 0..3

    const float* feat = (lvl==0) ? g0 : (lvl==1) ? g1 : (lvl==2) ? g2 : g3;
    const int    L    = (lvl==0) ? 200 : (lvl==1) ? 100 : (lvl==2) ? 50 : 25;
    const float scale = (lvl==0) ? 0.25f : (lvl==1) ? 0.125f
                      : (lvl==2) ? 0.0625f : 0.03125f;
    const int b  = batch_ids[n];
    const int LL = L * L;

    const float x1 = x1i * scale, y1 = y1i * scale;
    const float bw = fmaxf(x2i*scale - x1, 1.0f) * (1.0f/7.0f);
    const float bh = fmaxf(y2i*scale - y1, 1.0f) * (1.0f/7.0f);
    const float Lf = (float)L, Lm1 = Lf - 1.0f;
    const int   Lm2 = L - 2;

    // ---- region bounds -> SGPRs ----
    const int rx0 = rfl(min((int)fminf(fmaxf(x1 + 0.25f*bw, 0.0f), Lm1), Lm2));
    const int rx1 = rfl(min((int)fminf(fmaxf(x1 + 6.75f*bw, 0.0f), Lm1), Lm2));
    const int ry0 = rfl(min((int)fminf(fmaxf(y1 + 0.25f*bh, 0.0f), Lm1), Lm2));
    const int ry1 = rfl(min((int)fminf(fmaxf(y1 + 6.75f*bh, 0.0f), Lm1), Lm2));
    const int Hr  = ry1 - ry0 + 2;
    const int Hm1 = Hr - 1;

    // ---- width-class + aligned layout (all SALU) ----
    int path, rx0a, WrA, stride;
    if (lvl <= 1) {
        const int a4 = rx0 & ~3;
        const int W4 = (rx1 + 2 - a4 + 3) & ~3;
        const int s4 = ((W4 & 7) == 4) ? W4 : W4 + 4;
        if (W4 >= 16 && Hr * s4 <= LDS_CAP) {
            path = 0; rx0a = a4; WrA = W4; stride = s4;
        } else {
            path = 1; rx0a = rx0 & ~1;
            WrA = (rx1 + 2 - rx0a + 1) & ~1;
            stride = ((WrA & 3) == 2) ? WrA : WrA + 2;
        }
    } else if (lvl == 2) {
        path = 1; rx0a = rx0 & ~1;
        WrA = (rx1 + 2 - rx0a + 1) & ~1;
        stride = ((WrA & 3) == 2) ? WrA : WrA + 2;
    } else {
        path = 2; rx0a = rx0; WrA = rx1 + 2 - rx0;
        stride = WrA | 1;
    }
    if (Hr * stride > LDS_CAP) stride = WrA;   // safety net (near-never taken)

    // ---- interp prep ONCE (channel-independent) ----
    const int py = (lane < NPP) ? lane / P : 6;
    const int px = (lane < NPP) ? lane - py * P : 6;
    float wta[2][2], wtb[2][2], wtc[2][2], wtd[2][2];
    int   adr[2][2];
    {
        int   y0[2], x0[2];
        float fy[2], hy[2], vy[2], fx[2], hx[2], vx[2];
#pragma unroll
        for (int s = 0; s < 2; ++s) {
            const float yc = y1 + ((float)py + (s ? 0.75f : 0.25f)) * bh;
            vy[s] = (yc > -1.0f && yc < Lf) ? 1.0f : 0.0f;
            const float ycc = fminf(fmaxf(yc, 0.0f), Lm1);
            y0[s] = min((int)ycc, Lm2);
            fy[s] = ycc - (float)y0[s];
            hy[s] = 1.0f - fy[s];

            const float xc = x1 + ((float)px + (s ? 0.75f : 0.25f)) * bw;
            vx[s] = (xc > -1.0f && xc < Lf) ? 1.0f : 0.0f;
            const float xcc = fminf(fmaxf(xc, 0.0f), Lm1);
            x0[s] = min((int)xcc, Lm2);
            fx[s] = xcc - (float)x0[s];
            hx[s] = 1.0f - fx[s];
        }
#pragma unroll
        for (int sy = 0; sy < 2; ++sy)
#pragma unroll
        for (int sx = 0; sx < 2; ++sx) {
            const float w = 0.25f * vy[sy] * vx[sx];
            wta[sy][sx] = w * hy[sy] * hx[sx];
            wtb[sy][sx] = w * hy[sy] * fx[sx];
            wtc[sy][sx] = w * fy[sy] * hx[sx];
            wtd[sy][sx] = w * fy[sy] * fx[sx];
            adr[sy][sx] = (y0[sy] - ry0) * stride - rx0a + x0[sx];
        }
    }

    // ---- staging lane geometry ONCE (pow2 cols-per-row -> rows-per-pass) ----
    const int qpr  = WrA >> 2;
    const int p2q  = (qpr > 1) ? (32 - __clz(qpr - 1)) : 0;
    const int rp4  = 64 >> p2q;
    const int sub4 = lane >> p2q;
    const int cq4  = min((lane & ((1 << p2q) - 1)) << 2, WrA - 4);
    const int ppr  = WrA >> 1;
    const int p2p  = (ppr > 1) ? (32 - __clz(ppr - 1)) : 0;
    const int rp2  = 64 >> p2p;
    const int sub2 = lane >> p2p;
    const int cp2  = min((lane & ((1 << p2p) - 1)) << 1, WrA - 2);
    const int p2c  = (WrA > 1) ? (32 - __clz(WrA - 1)) : 0;
    const int rp1  = 64 >> p2c;
    const int sub1 = lane >> p2c;
    const int cc1  = min(lane & ((1 << p2c) - 1), WrA - 1);

    float* sp = sreg;
    const int c_first = cq * CHIT;
    size_t ob = ((size_t)n * NCH + c_first) * NPP + lane;

    for (int it = 0; it < CHIT; ++it) {
        const int poff = rfl((b * NCH + c_first + it) * LL + ry0 * L + rx0a);
        const float* gp = feat + poff;

        // ---- stage region -> LDS (2 row-groups per iter = 2 loads in flight) ----
        if (path == 0) {
            for (int r = 0; r < Hr; r += 2 * rp4) {
                const int rA = min(r + sub4, Hm1);
                const int rB = min(r + rp4 + sub4, Hm1);
                const f4 vA = *(const f4*)(gp + rA * L + cq4);
                const f4 vB = *(const f4*)(gp + rB * L + cq4);
                *(f4*)(sp + rA * stride + cq4) = vA;
                *(f4*)(sp + rB * stride + cq4) = vB;   // tail dup = same data
            }
        } else if (path == 1) {
            for (int r = 0; r < Hr; r += 2 * rp2) {
                const int rA = min(r + sub2, Hm1);
                const int rB = min(r + rp2 + sub2, Hm1);
                const f2 vA = *(const f2*)(gp + rA * L + cp2);
                const f2 vB = *(const f2*)(gp + rB * L + cp2);
                *(f2*)(sp + rA * stride + cp2) = vA;
                *(f2*)(sp + rB * stride + cp2) = vB;
            }
        } else {
            for (int r = 0; r < Hr; r += 2 * rp1) {
                const int rA = min(r + sub1, Hm1);
                const int rB = min(r + rp1 + sub1, Hm1);
                const float vA = gp[rA * L + cc1];
                const float vB = gp[rB * L + cc1];
                sp[rA * stride + cc1] = vA;
                sp[rB * stride + cc1] = vB;
            }
        }
        // NO barrier: sreg is block(=wave)-private; per-wave DS ops complete
        // in program order, so iter k's ds_reads finish before k+1's writes.

        // ---- interp from LDS (weights + addresses precomputed) ----
        if (lane < NPP) {
            float acc = 0.0f;
#pragma unroll
            for (int sy = 0; sy < 2; ++sy)
#pragma unroll
            for (int sx = 0; sx < 2; ++sx) {
                const int a = adr[sy][sx];
                acc += wta[sy][sx] * sp[a]
                     + wtb[sy][sx] * sp[a + 1]
                     + wtc[sy][sx] * sp[a + stride]
                     + wtd[sy][sx] * sp[a + stride + 1];
            }
            __builtin_nontemporal_store(acc, &out[ob]);   // out never re-read
        }
        ob += NPP;                                        // next channel
    }
}

extern "C" void kernel_launch(void* const* d_in, const int* in_sizes, int n_in,
                              void* d_out, int out_size, void* d_ws, size_t ws_size,
                              hipStream_t stream) {
    const float* boxes     = (const float*)d_in[0];
    const int*   batch_ids = (const int*)d_in[1];
    const float* g0        = (const float*)d_in[2];
    const float* g1        = (const float*)d_in[3];
    const float* g2        = (const float*)d_in[4];
    const float* g3        = (const float*)d_in[5];
    float* out = (float*)d_out;

    const int N = in_sizes[0] / 4;                 // 512
    dim3 block(64, 1);                             // 1 wave per block
    dim3 grid(NCH / CHIT, N);                      // (32, 512) = 16384 blocks
    pooler_kernel<<<grid, block, 0, stream>>>(boxes, batch_ids, g0, g1, g2, g3, out);
}